// Round 1
// baseline (407.684 us; speedup 1.0000x reference)
//
#include <hip/hip_runtime.h>

// ---------------------------------------------------------------------------
// WRGCN: 2-layer relational GCN.
//   per layer: skip = x@Wskip + bskip
//              hr[r] = h@Wrel[r]            (3 GEMMs)
//              msgs  = hr[type[e], src[e]] * w[e]
//              agg   = segment_sum(msgs, dst)
//              h     = agg + h@Wroot + bconv + skip
// Strategy: bf16 MFMA GEMMs (tolerance is bf16-class: 0.815 on |max|~40),
//           CSR-by-dst built on device once per launch -> atomic-free
//           per-node aggregation (one wave per node, f32 accumulate).
// ---------------------------------------------------------------------------

#define NNODES 50000
#define NEDGES 600000
#define DIM 128

typedef short short8 __attribute__((ext_vector_type(8)));
typedef float f32x4 __attribute__((ext_vector_type(4)));

__device__ __forceinline__ unsigned short f2bf(float f) {
    unsigned u = __float_as_uint(f);
    unsigned r = (u + 0x7FFFu + ((u >> 16) & 1u)) >> 16;   // RNE
    return (unsigned short)r;
}

// ---------------- weight prep: transpose + bf16, WT[l][slot][n][k] ---------
// slot 0..2 = w_rel[r]; slot 3 = w_root (+ w_skip if l==0); slot 4 = w_skip
__global__ void prep_w(const float* __restrict__ w_rel, const float* __restrict__ w_root,
                       const float* __restrict__ w_skip, unsigned short* __restrict__ WT) {
    int i = blockIdx.x * blockDim.x + threadIdx.x;
    if (i >= 2 * 5 * DIM * DIM) return;
    int k = i & 127;
    int n = (i >> 7) & 127;
    int s = (i >> 14) % 5;
    int l = i / (5 * DIM * DIM);
    float v;
    if (s < 3)      v = w_rel[(((size_t)l * 3 + s) * DIM + k) * DIM + n];
    else if (s == 3) {
        v = w_root[((size_t)l * DIM + k) * DIM + n];
        if (l == 0) v += w_skip[((size_t)k) * DIM + n];      // merge skip for layer0 (h==x)
    } else           v = w_skip[((size_t)l * DIM + k) * DIM + n];
    WT[i] = f2bf(v);
}

// ---------------- CSR build ------------------------------------------------
__global__ void count_kernel(const int* __restrict__ dst, int* __restrict__ counts, int E) {
    int i = blockIdx.x * blockDim.x + threadIdx.x;
    if (i < E) atomicAdd(&counts[dst[i]], 1);
}

__global__ void scan_kernel(const int* __restrict__ counts, int* __restrict__ offsets,
                            int* __restrict__ cursor, int n) {
    __shared__ int s[1024];
    int t = threadIdx.x;
    int CH = (n + 1023) / 1024;
    int begin = t * CH;
    int end = begin + CH; if (end > n) end = n; if (begin > n) begin = n;
    int sum = 0;
    for (int i = begin; i < end; ++i) sum += counts[i];
    s[t] = sum;
    __syncthreads();
    for (int d = 1; d < 1024; d <<= 1) {      // Hillis-Steele inclusive scan
        int v = (t >= d) ? s[t - d] : 0;
        __syncthreads();
        s[t] += v;
        __syncthreads();
    }
    int running = s[t] - sum;                 // exclusive prefix
    for (int i = begin; i < end; ++i) {
        offsets[i] = running;
        cursor[i]  = running;
        running += counts[i];
    }
    if (t == 1023) offsets[n] = running;      // == E
}

__global__ void scatter_kernel(const int* __restrict__ src, const int* __restrict__ dst,
                               const int* __restrict__ etype, const float* __restrict__ ew,
                               int* __restrict__ cursor, unsigned* __restrict__ csr_st,
                               float* __restrict__ csr_w, int E) {
    int i = blockIdx.x * blockDim.x + threadIdx.x;
    if (i >= E) return;
    int d = dst[i];
    int p = atomicAdd(&cursor[d], 1);
    csr_st[p] = (unsigned)src[i] | ((unsigned)etype[i] << 16);   // src<65536, type<4
    csr_w[p]  = ew[i];
}

// ---------------- fused GEMMs: hr[0..2] (bf16) + out-init (f32 + bias) -----
// A: [M][128] f32.  WT_layer: 4+ slots of [128 n][128 k] bf16 (pre-transposed).
__global__ __launch_bounds__(256) void multi_gemm(
    const float* __restrict__ A, const unsigned short* __restrict__ WT_layer,
    const float* __restrict__ bconv, const float* __restrict__ bskip,
    unsigned short* __restrict__ hr, float* __restrict__ outf, int M) {
    __shared__ unsigned short sA[64][136];    // +8 pad -> 2-way max bank alias
    __shared__ unsigned short sWt[128][136];
    int t = threadIdx.x;
    int row0 = blockIdx.x * 64;
    // stage A tile (f32 -> bf16)
    for (int i = 0; i < 8; ++i) {
        int idx = t + i * 256;
        int r = idx >> 5, c = (idx & 31) << 2;
        int gr = row0 + r;
        float4 v = make_float4(0.f, 0.f, 0.f, 0.f);
        if (gr < M) v = *reinterpret_cast<const float4*>(A + (size_t)gr * DIM + c);
        sA[r][c + 0] = f2bf(v.x); sA[r][c + 1] = f2bf(v.y);
        sA[r][c + 2] = f2bf(v.z); sA[r][c + 3] = f2bf(v.w);
    }
    int lane = t & 63, wid = t >> 6;
    int rA = wid * 16 + (lane & 15);
    int kc = (lane >> 4) << 3;
    int col_l = lane & 15;
    int rbase = row0 + wid * 16 + (lane >> 4) * 4;
    __syncthreads();
    short8 afr[4];
    for (int ks = 0; ks < 4; ++ks)
        afr[ks] = *reinterpret_cast<const short8*>(&sA[rA][ks * 32 + kc]);

    for (int s = 0; s < 4; ++s) {
        const uint4* wp = reinterpret_cast<const uint4*>(WT_layer + (size_t)s * DIM * DIM);
        for (int i = 0; i < 8; ++i) {
            int idx = t + i * 256;
            int n = idx >> 4, k8 = (idx & 15) << 3;
            *reinterpret_cast<uint4*>(&sWt[n][k8]) = wp[idx];
        }
        __syncthreads();
        for (int n = 0; n < 8; ++n) {
            f32x4 acc = {0.f, 0.f, 0.f, 0.f};
            for (int ks = 0; ks < 4; ++ks) {
                short8 b = *reinterpret_cast<const short8*>(&sWt[n * 16 + col_l][ks * 32 + kc]);
                acc = __builtin_amdgcn_mfma_f32_16x16x32_bf16(afr[ks], b, acc, 0, 0, 0);
            }
            int col = n * 16 + col_l;
            if (s < 3) {
                unsigned short* hp = hr + (size_t)s * M * DIM;
                for (int i2 = 0; i2 < 4; ++i2) {
                    int r = rbase + i2;
                    if (r < M) hp[(size_t)r * DIM + col] = f2bf(acc[i2]);
                }
            } else {
                float bb = bconv[col] + bskip[col];
                for (int i2 = 0; i2 < 4; ++i2) {
                    int r = rbase + i2;
                    if (r < M) outf[(size_t)r * DIM + col] = acc[i2] + bb;
                }
            }
        }
        __syncthreads();   // protect sWt before restaging
    }
}

// ---------------- skip GEMM (layer 1): out += x @ Wskip --------------------
__global__ __launch_bounds__(256) void gemm_acc(
    const float* __restrict__ A, const unsigned short* __restrict__ WTs,
    float* __restrict__ outf, int M) {
    __shared__ unsigned short sA[64][136];
    __shared__ unsigned short sWt[128][136];
    int t = threadIdx.x;
    int row0 = blockIdx.x * 64;
    for (int i = 0; i < 8; ++i) {
        int idx = t + i * 256;
        int r = idx >> 5, c = (idx & 31) << 2;
        int gr = row0 + r;
        float4 v = make_float4(0.f, 0.f, 0.f, 0.f);
        if (gr < M) v = *reinterpret_cast<const float4*>(A + (size_t)gr * DIM + c);
        sA[r][c + 0] = f2bf(v.x); sA[r][c + 1] = f2bf(v.y);
        sA[r][c + 2] = f2bf(v.z); sA[r][c + 3] = f2bf(v.w);
    }
    const uint4* wp = reinterpret_cast<const uint4*>(WTs);
    for (int i = 0; i < 8; ++i) {
        int idx = t + i * 256;
        int n = idx >> 4, k8 = (idx & 15) << 3;
        *reinterpret_cast<uint4*>(&sWt[n][k8]) = wp[idx];
    }
    int lane = t & 63, wid = t >> 6;
    int rA = wid * 16 + (lane & 15);
    int kc = (lane >> 4) << 3;
    int col_l = lane & 15;
    int rbase = row0 + wid * 16 + (lane >> 4) * 4;
    __syncthreads();
    short8 afr[4];
    for (int ks = 0; ks < 4; ++ks)
        afr[ks] = *reinterpret_cast<const short8*>(&sA[rA][ks * 32 + kc]);
    for (int n = 0; n < 8; ++n) {
        f32x4 acc = {0.f, 0.f, 0.f, 0.f};
        for (int ks = 0; ks < 4; ++ks) {
            short8 b = *reinterpret_cast<const short8*>(&sWt[n * 16 + col_l][ks * 32 + kc]);
            acc = __builtin_amdgcn_mfma_f32_16x16x32_bf16(afr[ks], b, acc, 0, 0, 0);
        }
        int col = n * 16 + col_l;
        for (int i2 = 0; i2 < 4; ++i2) {
            int r = rbase + i2;
            if (r < M) outf[(size_t)r * DIM + col] += acc[i2];
        }
    }
}

// ---------------- aggregation: one wave per node, no atomics ---------------
__global__ __launch_bounds__(256) void agg_kernel(
    const unsigned short* __restrict__ hr, const unsigned* __restrict__ csr_st,
    const float* __restrict__ csr_w, const int* __restrict__ offsets,
    float* __restrict__ out, int N) {
    int lane = threadIdx.x & 63;
    int v = blockIdx.x * 4 + (threadIdx.x >> 6);
    if (v >= N) return;
    int beg = offsets[v], end = offsets[v + 1];
    float ax = 0.f, ay = 0.f;                    // dims 2*lane, 2*lane+1
    for (int i = beg; i < end; ++i) {
        unsigned st = csr_st[i];                 // wave-uniform broadcast loads
        float w = csr_w[i];
        int srcn = st & 0xFFFF;
        int rel  = st >> 16;
        const unsigned short* row = hr + ((size_t)rel * N + srcn) * DIM;
        unsigned pv = *reinterpret_cast<const unsigned*>(row + lane * 2);
        float f0 = __uint_as_float(pv << 16);            // bf16 lo -> f32
        float f1 = __uint_as_float(pv & 0xFFFF0000u);    // bf16 hi -> f32
        ax += w * f0;
        ay += w * f1;
    }
    float2* op = reinterpret_cast<float2*>(out + (size_t)v * DIM) + lane;
    float2 cur = *op;
    cur.x += ax; cur.y += ay;
    *op = cur;
}

// ---------------------------------------------------------------------------
extern "C" void kernel_launch(void* const* d_in, const int* in_sizes, int n_in,
                              void* d_out, int out_size, void* d_ws, size_t ws_size,
                              hipStream_t stream) {
    const float* x       = (const float*)d_in[0];
    const int*   eidx    = (const int*)d_in[1];
    const int*   etype   = (const int*)d_in[2];
    const float* ew      = (const float*)d_in[3];
    const float* w_rel   = (const float*)d_in[4];
    const float* w_root  = (const float*)d_in[5];
    const float* b_conv  = (const float*)d_in[6];
    const float* w_skip  = (const float*)d_in[7];
    const float* b_skip  = (const float*)d_in[8];

    const int N = in_sizes[0] / DIM;          // 50000
    const int E = in_sizes[3];                // 600000
    const int* src = eidx;
    const int* dst = eidx + E;

    // ---- workspace carve (all 16B aligned); total ~66.5 MB ----
    char* w = (char*)d_ws;
    unsigned short* WT   = (unsigned short*)w;  w += (size_t)2 * 5 * DIM * DIM * 2;  // 327680
    unsigned short* hr   = (unsigned short*)w;  w += (size_t)3 * N * DIM * 2;        // 38.4MB
    float* h1            = (float*)w;           w += (size_t)N * DIM * 4;            // 25.6MB
    int* counts          = (int*)w;             w += (size_t)N * 4;
    int* offsets         = (int*)w;             w += (size_t)(N + 4) * 4;
    int* cursor          = (int*)w;             w += (size_t)N * 4;
    unsigned* csr_st     = (unsigned*)w;        w += (size_t)E * 4;
    float* csr_w         = (float*)w;           w += (size_t)E * 4;

    float* out = (float*)d_out;

    hipMemsetAsync(counts, 0, (size_t)N * sizeof(int), stream);
    prep_w<<<(2 * 5 * DIM * DIM + 255) / 256, 256, 0, stream>>>(w_rel, w_root, w_skip, WT);
    count_kernel<<<(E + 255) / 256, 256, 0, stream>>>(dst, counts, E);
    scan_kernel<<<1, 1024, 0, stream>>>(counts, offsets, cursor, N);
    scatter_kernel<<<(E + 255) / 256, 256, 0, stream>>>(src, dst, etype, ew,
                                                        cursor, csr_st, csr_w, E);
    int gblocks = (N + 63) / 64;
    int ablocks = (N + 3) / 4;
    // ---- layer 0 (h == x: root+skip merged in slot 3) ----
    multi_gemm<<<gblocks, 256, 0, stream>>>(x, WT, b_conv, b_skip, hr, h1, N);
    agg_kernel<<<ablocks, 256, 0, stream>>>(hr, csr_st, csr_w, offsets, h1, N);
    // ---- layer 1 ----
    multi_gemm<<<gblocks, 256, 0, stream>>>(h1, WT + (size_t)5 * DIM * DIM,
                                            b_conv + DIM, b_skip + DIM, hr, out, N);
    gemm_acc<<<gblocks, 256, 0, stream>>>(x, WT + (size_t)(5 + 4) * DIM * DIM, out, N);
    agg_kernel<<<ablocks, 256, 0, stream>>>(hr, csr_st, csr_w, offsets, out, N);
}

// Round 2
// 294.249 us; speedup vs baseline: 1.3855x; 1.3855x over previous
//
#include <hip/hip_runtime.h>

// ---------------------------------------------------------------------------
// WRGCN: 2-layer relational GCN.
// Round 2: (a) grid-wide 3-stage scan replaces the 110us single-block scan;
//          (b) layer-1 skip GEMM fused into multi_gemm as slot 4 (second
//              A-tile from x), eliminating gemm_acc's RMW pass over out.
// ---------------------------------------------------------------------------

#define NNODES 50000
#define NEDGES 600000
#define DIM 128

typedef short short8 __attribute__((ext_vector_type(8)));
typedef float f32x4 __attribute__((ext_vector_type(4)));

__device__ __forceinline__ unsigned short f2bf(float f) {
    unsigned u = __float_as_uint(f);
    unsigned r = (u + 0x7FFFu + ((u >> 16) & 1u)) >> 16;   // RNE
    return (unsigned short)r;
}

// ---------------- weight prep: transpose + bf16, WT[l][slot][n][k] ---------
// slot 0..2 = w_rel[r]; slot 3 = w_root (+ w_skip if l==0); slot 4 = w_skip
__global__ void prep_w(const float* __restrict__ w_rel, const float* __restrict__ w_root,
                       const float* __restrict__ w_skip, unsigned short* __restrict__ WT) {
    int i = blockIdx.x * blockDim.x + threadIdx.x;
    if (i >= 2 * 5 * DIM * DIM) return;
    int k = i & 127;
    int n = (i >> 7) & 127;
    int s = (i >> 14) % 5;
    int l = i / (5 * DIM * DIM);
    float v;
    if (s < 3)      v = w_rel[(((size_t)l * 3 + s) * DIM + k) * DIM + n];
    else if (s == 3) {
        v = w_root[((size_t)l * DIM + k) * DIM + n];
        if (l == 0) v += w_skip[((size_t)k) * DIM + n];      // merge skip for layer0 (h==x)
    } else           v = w_skip[((size_t)l * DIM + k) * DIM + n];
    WT[i] = f2bf(v);
}

// ---------------- CSR build ------------------------------------------------
__global__ void count_kernel(const int* __restrict__ dst, int* __restrict__ counts, int E) {
    int i = blockIdx.x * blockDim.x + threadIdx.x;
    if (i < E) atomicAdd(&counts[dst[i]], 1);
}

// stage 1: per-256-chunk sums
__global__ void bsum_kernel(const int* __restrict__ counts, int* __restrict__ bsums, int n) {
    int t = threadIdx.x;
    int i = blockIdx.x * 256 + t;
    int v = (i < n) ? counts[i] : 0;
    for (int d = 32; d; d >>= 1) v += __shfl_down(v, d);   // 64-lane reduce
    __shared__ int ws[4];
    if ((t & 63) == 0) ws[t >> 6] = v;
    __syncthreads();
    if (t == 0) bsums[blockIdx.x] = ws[0] + ws[1] + ws[2] + ws[3];
}

// stage 2: single-block scan of <=256 block sums (nblk=196)
__global__ void bscan_kernel(const int* __restrict__ bsums, int* __restrict__ bpre, int nblk) {
    __shared__ int s[256];
    int t = threadIdx.x;
    int v = (t < nblk) ? bsums[t] : 0;
    s[t] = v;
    __syncthreads();
    for (int d = 1; d < 256; d <<= 1) {
        int u = (t >= d) ? s[t - d] : 0;
        __syncthreads();
        s[t] += u;
        __syncthreads();
    }
    bpre[t] = s[t] - v;                       // exclusive prefix of block sums
}

// stage 3: per-chunk local scan + block offset -> offsets, cursor
__global__ void scan_final(const int* __restrict__ counts, const int* __restrict__ bpre,
                           int* __restrict__ offsets, int* __restrict__ cursor, int n, int E) {
    __shared__ int s[256];
    int t = threadIdx.x;
    int i = blockIdx.x * 256 + t;
    int v = (i < n) ? counts[i] : 0;
    s[t] = v;
    __syncthreads();
    for (int d = 1; d < 256; d <<= 1) {
        int u = (t >= d) ? s[t - d] : 0;
        __syncthreads();
        s[t] += u;
        __syncthreads();
    }
    int ex = s[t] - v + bpre[blockIdx.x];
    if (i < n) { offsets[i] = ex; cursor[i] = ex; }
    if (i == 0) offsets[n] = E;
}

__global__ void scatter_kernel(const int* __restrict__ src, const int* __restrict__ dst,
                               const int* __restrict__ etype, const float* __restrict__ ew,
                               int* __restrict__ cursor, unsigned* __restrict__ csr_st,
                               float* __restrict__ csr_w, int E) {
    int i = blockIdx.x * blockDim.x + threadIdx.x;
    if (i >= E) return;
    int d = dst[i];
    int p = atomicAdd(&cursor[d], 1);
    csr_st[p] = (unsigned)src[i] | ((unsigned)etype[i] << 16);   // src<65536, type<4
    csr_w[p]  = ew[i];
}

// ---------------- fused GEMMs ---------------------------------------------
// slots 0..2: hr[r] = A@Wrel[r] (bf16 out). slot 3: root from A.
// If Xs != null: slot 4 = skip from Xs, accumulated with slot 3, single store.
// Else: slot-3 result stored directly (layer 0: root+skip pre-merged).
__global__ __launch_bounds__(256) void multi_gemm(
    const float* __restrict__ A, const float* __restrict__ Xs,
    const unsigned short* __restrict__ WT_layer,
    const float* __restrict__ bconv, const float* __restrict__ bskip,
    unsigned short* __restrict__ hr, float* __restrict__ outf, int M) {
    __shared__ unsigned short sA[64][136];
    __shared__ unsigned short sX[64][136];
    __shared__ unsigned short sWt[128][136];
    int t = threadIdx.x;
    int row0 = blockIdx.x * 64;
    for (int i = 0; i < 8; ++i) {
        int idx = t + i * 256;
        int r = idx >> 5, c = (idx & 31) << 2;
        int gr = row0 + r;
        float4 v = make_float4(0.f, 0.f, 0.f, 0.f);
        if (gr < M) v = *reinterpret_cast<const float4*>(A + (size_t)gr * DIM + c);
        sA[r][c + 0] = f2bf(v.x); sA[r][c + 1] = f2bf(v.y);
        sA[r][c + 2] = f2bf(v.z); sA[r][c + 3] = f2bf(v.w);
    }
    if (Xs) {
        for (int i = 0; i < 8; ++i) {
            int idx = t + i * 256;
            int r = idx >> 5, c = (idx & 31) << 2;
            int gr = row0 + r;
            float4 v = make_float4(0.f, 0.f, 0.f, 0.f);
            if (gr < M) v = *reinterpret_cast<const float4*>(Xs + (size_t)gr * DIM + c);
            sX[r][c + 0] = f2bf(v.x); sX[r][c + 1] = f2bf(v.y);
            sX[r][c + 2] = f2bf(v.z); sX[r][c + 3] = f2bf(v.w);
        }
    }
    int lane = t & 63, wid = t >> 6;
    int rA = wid * 16 + (lane & 15);
    int kc = (lane >> 4) << 3;
    int col_l = lane & 15;
    int rbase = row0 + wid * 16 + (lane >> 4) * 4;
    __syncthreads();
    short8 afr[4], xfr[4];
    for (int ks = 0; ks < 4; ++ks)
        afr[ks] = *reinterpret_cast<const short8*>(&sA[rA][ks * 32 + kc]);
    if (Xs)
        for (int ks = 0; ks < 4; ++ks)
            xfr[ks] = *reinterpret_cast<const short8*>(&sX[rA][ks * 32 + kc]);

    int nslots = Xs ? 5 : 4;
    f32x4 acc3[8];
    for (int s = 0; s < nslots; ++s) {
        const uint4* wp = reinterpret_cast<const uint4*>(WT_layer + (size_t)s * DIM * DIM);
        for (int i = 0; i < 8; ++i) {
            int idx = t + i * 256;
            int n = idx >> 4, k8 = (idx & 15) << 3;
            *reinterpret_cast<uint4*>(&sWt[n][k8]) = wp[idx];
        }
        __syncthreads();
        for (int n = 0; n < 8; ++n) {
            f32x4 acc = (s == 4) ? acc3[n] : f32x4{0.f, 0.f, 0.f, 0.f};
            for (int ks = 0; ks < 4; ++ks) {
                short8 b = *reinterpret_cast<const short8*>(&sWt[n * 16 + col_l][ks * 32 + kc]);
                acc = __builtin_amdgcn_mfma_f32_16x16x32_bf16((s == 4) ? xfr[ks] : afr[ks],
                                                              b, acc, 0, 0, 0);
            }
            int col = n * 16 + col_l;
            if (s < 3) {
                unsigned short* hp = hr + (size_t)s * M * DIM;
                for (int i2 = 0; i2 < 4; ++i2) {
                    int r = rbase + i2;
                    if (r < M) hp[(size_t)r * DIM + col] = f2bf(acc[i2]);
                }
            } else if (s == 3 && Xs) {
                acc3[n] = acc;                 // hold root result for skip fusion
            } else {
                float bb = bconv[col] + bskip[col];
                for (int i2 = 0; i2 < 4; ++i2) {
                    int r = rbase + i2;
                    if (r < M) outf[(size_t)r * DIM + col] = acc[i2] + bb;
                }
            }
        }
        __syncthreads();   // protect sWt before restaging
    }
}

// ---------------- aggregation: one wave per node, no atomics ---------------
__global__ __launch_bounds__(256) void agg_kernel(
    const unsigned short* __restrict__ hr, const unsigned* __restrict__ csr_st,
    const float* __restrict__ csr_w, const int* __restrict__ offsets,
    float* __restrict__ out, int N) {
    int lane = threadIdx.x & 63;
    int v = blockIdx.x * 4 + (threadIdx.x >> 6);
    if (v >= N) return;
    int beg = offsets[v], end = offsets[v + 1];
    float ax = 0.f, ay = 0.f;                    // dims 2*lane, 2*lane+1
    for (int i = beg; i < end; ++i) {
        unsigned st = csr_st[i];                 // wave-uniform broadcast loads
        float w = csr_w[i];
        int srcn = st & 0xFFFF;
        int rel  = st >> 16;
        const unsigned short* row = hr + ((size_t)rel * N + srcn) * DIM;
        unsigned pv = *reinterpret_cast<const unsigned*>(row + lane * 2);
        float f0 = __uint_as_float(pv << 16);            // bf16 lo -> f32
        float f1 = __uint_as_float(pv & 0xFFFF0000u);    // bf16 hi -> f32
        ax += w * f0;
        ay += w * f1;
    }
    float2* op = reinterpret_cast<float2*>(out + (size_t)v * DIM) + lane;
    float2 cur = *op;
    cur.x += ax; cur.y += ay;
    *op = cur;
}

// ---------------------------------------------------------------------------
extern "C" void kernel_launch(void* const* d_in, const int* in_sizes, int n_in,
                              void* d_out, int out_size, void* d_ws, size_t ws_size,
                              hipStream_t stream) {
    const float* x       = (const float*)d_in[0];
    const int*   eidx    = (const int*)d_in[1];
    const int*   etype   = (const int*)d_in[2];
    const float* ew      = (const float*)d_in[3];
    const float* w_rel   = (const float*)d_in[4];
    const float* w_root  = (const float*)d_in[5];
    const float* b_conv  = (const float*)d_in[6];
    const float* w_skip  = (const float*)d_in[7];
    const float* b_skip  = (const float*)d_in[8];

    const int N = in_sizes[0] / DIM;          // 50000
    const int E = in_sizes[3];                // 600000
    const int* src = eidx;
    const int* dst = eidx + E;
    const int nblk = (N + 255) / 256;         // 196 (<=256 required by bscan)

    // ---- workspace carve (all 16B aligned) ----
    char* w = (char*)d_ws;
    unsigned short* WT   = (unsigned short*)w;  w += (size_t)2 * 5 * DIM * DIM * 2;
    unsigned short* hr   = (unsigned short*)w;  w += (size_t)3 * N * DIM * 2;        // 38.4MB
    float* h1            = (float*)w;           w += (size_t)N * DIM * 4;            // 25.6MB
    int* counts          = (int*)w;             w += (size_t)N * 4;
    int* offsets         = (int*)w;             w += (size_t)(N + 4) * 4;
    int* cursor          = (int*)w;             w += (size_t)N * 4;
    int* bsums           = (int*)w;             w += (size_t)256 * 4;
    int* bpre            = (int*)w;             w += (size_t)256 * 4;
    unsigned* csr_st     = (unsigned*)w;        w += (size_t)E * 4;
    float* csr_w         = (float*)w;           w += (size_t)E * 4;

    float* out = (float*)d_out;

    hipMemsetAsync(counts, 0, (size_t)N * sizeof(int), stream);
    prep_w<<<(2 * 5 * DIM * DIM + 255) / 256, 256, 0, stream>>>(w_rel, w_root, w_skip, WT);
    count_kernel<<<(E + 255) / 256, 256, 0, stream>>>(dst, counts, E);
    bsum_kernel<<<nblk, 256, 0, stream>>>(counts, bsums, N);
    bscan_kernel<<<1, 256, 0, stream>>>(bsums, bpre, nblk);
    scan_final<<<nblk, 256, 0, stream>>>(counts, bpre, offsets, cursor, N, E);
    scatter_kernel<<<(E + 255) / 256, 256, 0, stream>>>(src, dst, etype, ew,
                                                        cursor, csr_st, csr_w, E);
    int gblocks = (N + 63) / 64;
    int ablocks = (N + 3) / 4;
    // ---- layer 0 (h == x: root+skip merged in slot 3) ----
    multi_gemm<<<gblocks, 256, 0, stream>>>(x, nullptr, WT, b_conv, b_skip, hr, h1, N);
    agg_kernel<<<ablocks, 256, 0, stream>>>(hr, csr_st, csr_w, offsets, h1, N);
    // ---- layer 1 (root from h1, skip from x fused as slot 4) ----
    multi_gemm<<<gblocks, 256, 0, stream>>>(h1, x, WT + (size_t)5 * DIM * DIM,
                                            b_conv + DIM, b_skip + DIM, hr, out, N);
    agg_kernel<<<ablocks, 256, 0, stream>>>(hr, csr_st, csr_w, offsets, out, N);
}

// Round 3
// 228.116 us; speedup vs baseline: 1.7872x; 1.2899x over previous
//
#include <hip/hip_runtime.h>

// ---------------------------------------------------------------------------
// WRGCN: 2-layer relational GCN.
// Round 3: agg_kernel reworked for memory-level parallelism — 4 edges in
// flight per wave (16-lane groups, 8 dims/lane via uint4 bf16 loads) plus
// next-edge descriptor prefetch. Was: 1 edge at a time, latency-bound at
// 21% HBM / 19% VALU.
// ---------------------------------------------------------------------------

#define NNODES 50000
#define NEDGES 600000
#define DIM 128

typedef short short8 __attribute__((ext_vector_type(8)));
typedef float f32x4 __attribute__((ext_vector_type(4)));

__device__ __forceinline__ unsigned short f2bf(float f) {
    unsigned u = __float_as_uint(f);
    unsigned r = (u + 0x7FFFu + ((u >> 16) & 1u)) >> 16;   // RNE
    return (unsigned short)r;
}
__device__ __forceinline__ float bflo(unsigned p) { return __uint_as_float(p << 16); }
__device__ __forceinline__ float bfhi(unsigned p) { return __uint_as_float(p & 0xFFFF0000u); }

// ---------------- weight prep: transpose + bf16, WT[l][slot][n][k] ---------
// slot 0..2 = w_rel[r]; slot 3 = w_root (+ w_skip if l==0); slot 4 = w_skip
__global__ void prep_w(const float* __restrict__ w_rel, const float* __restrict__ w_root,
                       const float* __restrict__ w_skip, unsigned short* __restrict__ WT) {
    int i = blockIdx.x * blockDim.x + threadIdx.x;
    if (i >= 2 * 5 * DIM * DIM) return;
    int k = i & 127;
    int n = (i >> 7) & 127;
    int s = (i >> 14) % 5;
    int l = i / (5 * DIM * DIM);
    float v;
    if (s < 3)      v = w_rel[(((size_t)l * 3 + s) * DIM + k) * DIM + n];
    else if (s == 3) {
        v = w_root[((size_t)l * DIM + k) * DIM + n];
        if (l == 0) v += w_skip[((size_t)k) * DIM + n];      // merge skip for layer0 (h==x)
    } else           v = w_skip[((size_t)l * DIM + k) * DIM + n];
    WT[i] = f2bf(v);
}

// ---------------- CSR build ------------------------------------------------
__global__ void count_kernel(const int* __restrict__ dst, int* __restrict__ counts, int E) {
    int i = blockIdx.x * blockDim.x + threadIdx.x;
    if (i < E) atomicAdd(&counts[dst[i]], 1);
}

__global__ void bsum_kernel(const int* __restrict__ counts, int* __restrict__ bsums, int n) {
    int t = threadIdx.x;
    int i = blockIdx.x * 256 + t;
    int v = (i < n) ? counts[i] : 0;
    for (int d = 32; d; d >>= 1) v += __shfl_down(v, d);   // 64-lane reduce
    __shared__ int ws[4];
    if ((t & 63) == 0) ws[t >> 6] = v;
    __syncthreads();
    if (t == 0) bsums[blockIdx.x] = ws[0] + ws[1] + ws[2] + ws[3];
}

__global__ void bscan_kernel(const int* __restrict__ bsums, int* __restrict__ bpre, int nblk) {
    __shared__ int s[256];
    int t = threadIdx.x;
    int v = (t < nblk) ? bsums[t] : 0;
    s[t] = v;
    __syncthreads();
    for (int d = 1; d < 256; d <<= 1) {
        int u = (t >= d) ? s[t - d] : 0;
        __syncthreads();
        s[t] += u;
        __syncthreads();
    }
    bpre[t] = s[t] - v;                       // exclusive prefix of block sums
}

__global__ void scan_final(const int* __restrict__ counts, const int* __restrict__ bpre,
                           int* __restrict__ offsets, int* __restrict__ cursor, int n, int E) {
    __shared__ int s[256];
    int t = threadIdx.x;
    int i = blockIdx.x * 256 + t;
    int v = (i < n) ? counts[i] : 0;
    s[t] = v;
    __syncthreads();
    for (int d = 1; d < 256; d <<= 1) {
        int u = (t >= d) ? s[t - d] : 0;
        __syncthreads();
        s[t] += u;
        __syncthreads();
    }
    int ex = s[t] - v + bpre[blockIdx.x];
    if (i < n) { offsets[i] = ex; cursor[i] = ex; }
    if (i == 0) offsets[n] = E;
}

__global__ void scatter_kernel(const int* __restrict__ src, const int* __restrict__ dst,
                               const int* __restrict__ etype, const float* __restrict__ ew,
                               int* __restrict__ cursor, unsigned* __restrict__ csr_st,
                               float* __restrict__ csr_w, int E) {
    int i = blockIdx.x * blockDim.x + threadIdx.x;
    if (i >= E) return;
    int d = dst[i];
    int p = atomicAdd(&cursor[d], 1);
    csr_st[p] = (unsigned)src[i] | ((unsigned)etype[i] << 16);   // src<65536, type<4
    csr_w[p]  = ew[i];
}

// ---------------- fused GEMMs ---------------------------------------------
// slots 0..2: hr[r] = A@Wrel[r] (bf16 out). slot 3: root from A.
// If Xs != null: slot 4 = skip from Xs, accumulated with slot 3, single store.
__global__ __launch_bounds__(256) void multi_gemm(
    const float* __restrict__ A, const float* __restrict__ Xs,
    const unsigned short* __restrict__ WT_layer,
    const float* __restrict__ bconv, const float* __restrict__ bskip,
    unsigned short* __restrict__ hr, float* __restrict__ outf, int M) {
    __shared__ unsigned short sA[64][136];
    __shared__ unsigned short sX[64][136];
    __shared__ unsigned short sWt[128][136];
    int t = threadIdx.x;
    int row0 = blockIdx.x * 64;
    for (int i = 0; i < 8; ++i) {
        int idx = t + i * 256;
        int r = idx >> 5, c = (idx & 31) << 2;
        int gr = row0 + r;
        float4 v = make_float4(0.f, 0.f, 0.f, 0.f);
        if (gr < M) v = *reinterpret_cast<const float4*>(A + (size_t)gr * DIM + c);
        sA[r][c + 0] = f2bf(v.x); sA[r][c + 1] = f2bf(v.y);
        sA[r][c + 2] = f2bf(v.z); sA[r][c + 3] = f2bf(v.w);
    }
    if (Xs) {
        for (int i = 0; i < 8; ++i) {
            int idx = t + i * 256;
            int r = idx >> 5, c = (idx & 31) << 2;
            int gr = row0 + r;
            float4 v = make_float4(0.f, 0.f, 0.f, 0.f);
            if (gr < M) v = *reinterpret_cast<const float4*>(Xs + (size_t)gr * DIM + c);
            sX[r][c + 0] = f2bf(v.x); sX[r][c + 1] = f2bf(v.y);
            sX[r][c + 2] = f2bf(v.z); sX[r][c + 3] = f2bf(v.w);
        }
    }
    int lane = t & 63, wid = t >> 6;
    int rA = wid * 16 + (lane & 15);
    int kc = (lane >> 4) << 3;
    int col_l = lane & 15;
    int rbase = row0 + wid * 16 + (lane >> 4) * 4;
    __syncthreads();
    short8 afr[4], xfr[4];
    for (int ks = 0; ks < 4; ++ks)
        afr[ks] = *reinterpret_cast<const short8*>(&sA[rA][ks * 32 + kc]);
    if (Xs)
        for (int ks = 0; ks < 4; ++ks)
            xfr[ks] = *reinterpret_cast<const short8*>(&sX[rA][ks * 32 + kc]);

    int nslots = Xs ? 5 : 4;
    f32x4 acc3[8];
    for (int s = 0; s < nslots; ++s) {
        const uint4* wp = reinterpret_cast<const uint4*>(WT_layer + (size_t)s * DIM * DIM);
        for (int i = 0; i < 8; ++i) {
            int idx = t + i * 256;
            int n = idx >> 4, k8 = (idx & 15) << 3;
            *reinterpret_cast<uint4*>(&sWt[n][k8]) = wp[idx];
        }
        __syncthreads();
        for (int n = 0; n < 8; ++n) {
            f32x4 acc = (s == 4) ? acc3[n] : f32x4{0.f, 0.f, 0.f, 0.f};
            for (int ks = 0; ks < 4; ++ks) {
                short8 b = *reinterpret_cast<const short8*>(&sWt[n * 16 + col_l][ks * 32 + kc]);
                acc = __builtin_amdgcn_mfma_f32_16x16x32_bf16((s == 4) ? xfr[ks] : afr[ks],
                                                              b, acc, 0, 0, 0);
            }
            int col = n * 16 + col_l;
            if (s < 3) {
                unsigned short* hp = hr + (size_t)s * M * DIM;
                for (int i2 = 0; i2 < 4; ++i2) {
                    int r = rbase + i2;
                    if (r < M) hp[(size_t)r * DIM + col] = f2bf(acc[i2]);
                }
            } else if (s == 3 && Xs) {
                acc3[n] = acc;                 // hold root result for skip fusion
            } else {
                float bb = bconv[col] + bskip[col];
                for (int i2 = 0; i2 < 4; ++i2) {
                    int r = rbase + i2;
                    if (r < M) outf[(size_t)r * DIM + col] = acc[i2] + bb;
                }
            }
        }
        __syncthreads();   // protect sWt before restaging
    }
}

// ---------------- aggregation: 4 edges in flight per wave ------------------
// Wave = 4 groups x 16 lanes. Group g handles edges beg+g, beg+g+4, ...
// Lane covers 8 dims (one uint4 = 8 bf16). Cross-group shfl_xor combine.
__global__ __launch_bounds__(256) void agg_kernel(
    const unsigned short* __restrict__ hr, const unsigned* __restrict__ csr_st,
    const float* __restrict__ csr_w, const int* __restrict__ offsets,
    float* __restrict__ out, int N) {
    int t = threadIdx.x;
    int lane = t & 63;
    int v = blockIdx.x * 4 + (t >> 6);
    if (v >= N) return;
    int g = lane >> 4;          // edge slot 0..3
    int l16 = lane & 15;        // dim block: dims l16*8 .. l16*8+7
    int beg = offsets[v], end = offsets[v + 1];

    float acc[8] = {0.f, 0.f, 0.f, 0.f, 0.f, 0.f, 0.f, 0.f};
    int i = beg + g;
    bool valid = i < end;
    unsigned st = 0; float w = 0.f;
    if (valid) { st = csr_st[i]; w = csr_w[i]; }
    while (__any(valid)) {
        int ni = i + 4;
        bool nvalid = ni < end;
        unsigned nst = 0; float nw = 0.f;
        if (nvalid) { nst = csr_st[ni]; nw = csr_w[ni]; }      // prefetch next descriptor
        if (valid) {
            int srcn = st & 0xFFFF;
            int rel  = st >> 16;
            const unsigned short* row = hr + ((size_t)rel * N + srcn) * DIM + l16 * 8;
            uint4 pv = *reinterpret_cast<const uint4*>(row);
            acc[0] += w * bflo(pv.x); acc[1] += w * bfhi(pv.x);
            acc[2] += w * bflo(pv.y); acc[3] += w * bfhi(pv.y);
            acc[4] += w * bflo(pv.z); acc[5] += w * bfhi(pv.z);
            acc[6] += w * bflo(pv.w); acc[7] += w * bfhi(pv.w);
        }
        i = ni; st = nst; w = nw; valid = nvalid;
    }
    // combine the 4 groups: xor-16 then xor-32 gives every lane the total
    #pragma unroll
    for (int j = 0; j < 8; ++j) {
        acc[j] += __shfl_xor(acc[j], 16);
        acc[j] += __shfl_xor(acc[j], 32);
    }
    if (g == 0) {
        float* op = out + (size_t)v * DIM + l16 * 8;
        float4 c0 = *reinterpret_cast<float4*>(op);
        float4 c1 = *reinterpret_cast<float4*>(op + 4);
        c0.x += acc[0]; c0.y += acc[1]; c0.z += acc[2]; c0.w += acc[3];
        c1.x += acc[4]; c1.y += acc[5]; c1.z += acc[6]; c1.w += acc[7];
        *reinterpret_cast<float4*>(op) = c0;
        *reinterpret_cast<float4*>(op + 4) = c1;
    }
}

// ---------------------------------------------------------------------------
extern "C" void kernel_launch(void* const* d_in, const int* in_sizes, int n_in,
                              void* d_out, int out_size, void* d_ws, size_t ws_size,
                              hipStream_t stream) {
    const float* x       = (const float*)d_in[0];
    const int*   eidx    = (const int*)d_in[1];
    const int*   etype   = (const int*)d_in[2];
    const float* ew      = (const float*)d_in[3];
    const float* w_rel   = (const float*)d_in[4];
    const float* w_root  = (const float*)d_in[5];
    const float* b_conv  = (const float*)d_in[6];
    const float* w_skip  = (const float*)d_in[7];
    const float* b_skip  = (const float*)d_in[8];

    const int N = in_sizes[0] / DIM;          // 50000
    const int E = in_sizes[3];                // 600000
    const int* src = eidx;
    const int* dst = eidx + E;
    const int nblk = (N + 255) / 256;         // 196 (<=256 required by bscan)

    // ---- workspace carve (all 16B aligned) ----
    char* w = (char*)d_ws;
    unsigned short* WT   = (unsigned short*)w;  w += (size_t)2 * 5 * DIM * DIM * 2;
    unsigned short* hr   = (unsigned short*)w;  w += (size_t)3 * N * DIM * 2;        // 38.4MB
    float* h1            = (float*)w;           w += (size_t)N * DIM * 4;            // 25.6MB
    int* counts          = (int*)w;             w += (size_t)N * 4;
    int* offsets         = (int*)w;             w += (size_t)(N + 4) * 4;
    int* cursor          = (int*)w;             w += (size_t)N * 4;
    int* bsums           = (int*)w;             w += (size_t)256 * 4;
    int* bpre            = (int*)w;             w += (size_t)256 * 4;
    unsigned* csr_st     = (unsigned*)w;        w += (size_t)E * 4;
    float* csr_w         = (float*)w;           w += (size_t)E * 4;

    float* out = (float*)d_out;

    hipMemsetAsync(counts, 0, (size_t)N * sizeof(int), stream);
    prep_w<<<(2 * 5 * DIM * DIM + 255) / 256, 256, 0, stream>>>(w_rel, w_root, w_skip, WT);
    count_kernel<<<(E + 255) / 256, 256, 0, stream>>>(dst, counts, E);
    bsum_kernel<<<nblk, 256, 0, stream>>>(counts, bsums, N);
    bscan_kernel<<<1, 256, 0, stream>>>(bsums, bpre, nblk);
    scan_final<<<nblk, 256, 0, stream>>>(counts, bpre, offsets, cursor, N, E);
    scatter_kernel<<<(E + 255) / 256, 256, 0, stream>>>(src, dst, etype, ew,
                                                        cursor, csr_st, csr_w, E);
    int gblocks = (N + 63) / 64;
    int ablocks = (N + 3) / 4;
    // ---- layer 0 (h == x: root+skip merged in slot 3) ----
    multi_gemm<<<gblocks, 256, 0, stream>>>(x, nullptr, WT, b_conv, b_skip, hr, h1, N);
    agg_kernel<<<ablocks, 256, 0, stream>>>(hr, csr_st, csr_w, offsets, h1, N);
    // ---- layer 1 (root from h1, skip from x fused as slot 4) ----
    multi_gemm<<<gblocks, 256, 0, stream>>>(h1, x, WT + (size_t)5 * DIM * DIM,
                                            b_conv + DIM, b_skip + DIM, hr, out, N);
    agg_kernel<<<ablocks, 256, 0, stream>>>(hr, csr_st, csr_w, offsets, out, N);
}

// Round 4
// 204.190 us; speedup vs baseline: 1.9966x; 1.1172x over previous
//
#include <hip/hip_runtime.h>

// ---------------------------------------------------------------------------
// WRGCN round 4:
//  - scatter: single packed uint per edge (src|rel|w14) -> 1 store, 2.4MB CSR
//  - multi_gemm: LDS-free. B pre-packed fragment-linear (coalesced L2 loads),
//    A/X read as pre-converted bf16 direct to registers. 32 rows/wave.
//  - h between layers kept bf16 (gemm0 writes bf16, agg0 RMWs bf16).
// ---------------------------------------------------------------------------

#define DIM 128

typedef short short8 __attribute__((ext_vector_type(8)));
typedef float f32x4 __attribute__((ext_vector_type(4)));

__device__ __forceinline__ unsigned short f2bf(float f) {
    unsigned u = __float_as_uint(f);
    unsigned r = (u + 0x7FFFu + ((u >> 16) & 1u)) >> 16;   // RNE
    return (unsigned short)r;
}
__device__ __forceinline__ float bflo(unsigned p) { return __uint_as_float(p << 16); }
__device__ __forceinline__ float bfhi(unsigned p) { return __uint_as_float(p & 0xFFFF0000u); }

// ---------------- x -> bf16 (8 elems/thread) -------------------------------
__global__ void conv_bf16(const float* __restrict__ in, unsigned short* __restrict__ ob, int n8) {
    int i = blockIdx.x * 256 + threadIdx.x;
    if (i >= n8) return;
    const float4* ip = reinterpret_cast<const float4*>(in) + (size_t)i * 2;
    float4 v0 = ip[0], v1 = ip[1];
    uint4 o;
    o.x = (unsigned)f2bf(v0.x) | ((unsigned)f2bf(v0.y) << 16);
    o.y = (unsigned)f2bf(v0.z) | ((unsigned)f2bf(v0.w) << 16);
    o.z = (unsigned)f2bf(v1.x) | ((unsigned)f2bf(v1.y) << 16);
    o.w = (unsigned)f2bf(v1.z) | ((unsigned)f2bf(v1.w) << 16);
    reinterpret_cast<uint4*>(ob)[i] = o;
}

// ---------------- weight prep: fragment-linear bf16 ------------------------
// WTf[l][slot][n][ks][lane][j]: value = W_slot[k = ks*32+(lane>>4)*8+j][col = n*16+(lane&15)]
// slot 0..2 = w_rel[r]; slot 3 = w_root (+ w_skip if l==0); slot 4 = w_skip
__global__ void prep_w(const float* __restrict__ w_rel, const float* __restrict__ w_root,
                       const float* __restrict__ w_skip, unsigned short* __restrict__ WTf) {
    int i = blockIdx.x * blockDim.x + threadIdx.x;
    if (i >= 2 * 5 * DIM * DIM) return;
    int j    = i & 7;
    int lane = (i >> 3) & 63;
    int ks   = (i >> 9) & 3;
    int n    = (i >> 11) & 7;
    int s    = (i >> 14) % 5;
    int l    = i / (5 * DIM * DIM);
    int col = n * 16 + (lane & 15);
    int k   = ks * 32 + (lane >> 4) * 8 + j;
    float v;
    if (s < 3)       v = w_rel[(((size_t)l * 3 + s) * DIM + k) * DIM + col];
    else if (s == 3) {
        v = w_root[((size_t)l * DIM + k) * DIM + col];
        if (l == 0) v += w_skip[((size_t)k) * DIM + col];
    } else           v = w_skip[((size_t)l * DIM + k) * DIM + col];
    WTf[i] = f2bf(v);
}

// ---------------- CSR build ------------------------------------------------
__global__ void count_kernel(const int* __restrict__ dst, int* __restrict__ counts, int E) {
    int i = blockIdx.x * blockDim.x + threadIdx.x;
    if (i < E) atomicAdd(&counts[dst[i]], 1);
}

__global__ void bsum_kernel(const int* __restrict__ counts, int* __restrict__ bsums, int n) {
    int t = threadIdx.x;
    int i = blockIdx.x * 256 + t;
    int v = (i < n) ? counts[i] : 0;
    for (int d = 32; d; d >>= 1) v += __shfl_down(v, d);
    __shared__ int ws[4];
    if ((t & 63) == 0) ws[t >> 6] = v;
    __syncthreads();
    if (t == 0) bsums[blockIdx.x] = ws[0] + ws[1] + ws[2] + ws[3];
}

__global__ void bscan_kernel(const int* __restrict__ bsums, int* __restrict__ bpre, int nblk) {
    __shared__ int s[256];
    int t = threadIdx.x;
    int v = (t < nblk) ? bsums[t] : 0;
    s[t] = v;
    __syncthreads();
    for (int d = 1; d < 256; d <<= 1) {
        int u = (t >= d) ? s[t - d] : 0;
        __syncthreads();
        s[t] += u;
        __syncthreads();
    }
    bpre[t] = s[t] - v;
}

__global__ void scan_final(const int* __restrict__ counts, const int* __restrict__ bpre,
                           int* __restrict__ offsets, int* __restrict__ cursor, int n, int E) {
    __shared__ int s[256];
    int t = threadIdx.x;
    int i = blockIdx.x * 256 + t;
    int v = (i < n) ? counts[i] : 0;
    s[t] = v;
    __syncthreads();
    for (int d = 1; d < 256; d <<= 1) {
        int u = (t >= d) ? s[t - d] : 0;
        __syncthreads();
        s[t] += u;
        __syncthreads();
    }
    int ex = s[t] - v + bpre[blockIdx.x];
    if (i < n) { offsets[i] = ex; cursor[i] = ex; }
    if (i == 0) offsets[n] = E;
}

// packed record: src(16) | rel(2)<<16 | wq(14)<<18, wq = round(w*16383)
__global__ void scatter_kernel(const int* __restrict__ src, const int* __restrict__ dst,
                               const int* __restrict__ etype, const float* __restrict__ ew,
                               int* __restrict__ cursor, unsigned* __restrict__ csr, int E) {
    int i = blockIdx.x * blockDim.x + threadIdx.x;
    if (i >= E) return;
    int d = dst[i];
    int p = atomicAdd(&cursor[d], 1);
    unsigned wq = (unsigned)__float2uint_rn(ew[i] * 16383.0f);
    csr[p] = (unsigned)src[i] | ((unsigned)etype[i] << 16) | (wq << 18);
}

// ---------------- LDS-free fused GEMMs -------------------------------------
// 4 waves x 32 rows = 128 rows/block. B-frags from fragment-linear WTf
// (L2-hot coalesced), A/X-frags direct bf16 loads. Double-buffered B.
template<bool HAS_SKIP, bool OUT_BF16>
__global__ __launch_bounds__(256) void multi_gemm(
    const unsigned short* __restrict__ Ab, const unsigned short* __restrict__ Xb,
    const unsigned short* __restrict__ WTf,
    const float* __restrict__ bconv, const float* __restrict__ bskip,
    unsigned short* __restrict__ hr, void* __restrict__ outp, int M) {
    constexpr int NF = HAS_SKIP ? 40 : 32;
    int t = threadIdx.x, lane = t & 63, wid = t >> 6;
    int lrow = lane & 15, lhi = lane >> 4;
    int r0 = blockIdx.x * 128 + wid * 32;

    short8 af[2][4];
    #pragma unroll
    for (int rg = 0; rg < 2; ++rg) {
        int r = r0 + rg * 16 + lrow;
        const unsigned short* ap = Ab + (size_t)(r < M ? r : 0) * DIM + lhi * 8;
        #pragma unroll
        for (int ks = 0; ks < 4; ++ks)
            af[rg][ks] = *reinterpret_cast<const short8*>(ap + ks * 32);
    }
    short8 xf[2][4];        // HAS_SKIP only (loaded at slot-3 entry)
    f32x4 acc34[2][8];      // HAS_SKIP: persists slot3 -> slot4

    short8 b0[4], b1[4];
    auto loadB = [&](int fi, short8* bb) {
        const unsigned short* p = WTf + ((size_t)fi * 4 * 64 + lane) * 8;
        #pragma unroll
        for (int ks = 0; ks < 4; ++ks)
            bb[ks] = *reinterpret_cast<const short8*>(p + ks * 512);
    };
    loadB(0, b0);
    #pragma unroll
    for (int fi = 0; fi < NF; ++fi) {
        short8* bc = (fi & 1) ? b1 : b0;
        short8* bn = (fi & 1) ? b0 : b1;
        if (fi + 1 < NF) loadB(fi + 1, bn);
        const int slot = fi >> 3, n = fi & 7;
        const int col = n * 16 + lrow;
        if (HAS_SKIP && slot == 3 && n == 0) {
            #pragma unroll
            for (int rg = 0; rg < 2; ++rg) {
                int r = r0 + rg * 16 + lrow;
                const unsigned short* xp = Xb + (size_t)(r < M ? r : 0) * DIM + lhi * 8;
                #pragma unroll
                for (int ks = 0; ks < 4; ++ks)
                    xf[rg][ks] = *reinterpret_cast<const short8*>(xp + ks * 32);
            }
        }
        if (slot < 3) {
            f32x4 a0 = {0.f, 0.f, 0.f, 0.f}, a1 = {0.f, 0.f, 0.f, 0.f};
            #pragma unroll
            for (int ks = 0; ks < 4; ++ks) {
                a0 = __builtin_amdgcn_mfma_f32_16x16x32_bf16(af[0][ks], bc[ks], a0, 0, 0, 0);
                a1 = __builtin_amdgcn_mfma_f32_16x16x32_bf16(af[1][ks], bc[ks], a1, 0, 0, 0);
            }
            unsigned short* hp = hr + (size_t)slot * M * DIM;
            #pragma unroll
            for (int rg = 0; rg < 2; ++rg) {
                f32x4& aa = rg ? a1 : a0;
                #pragma unroll
                for (int i2 = 0; i2 < 4; ++i2) {
                    int r = r0 + rg * 16 + lhi * 4 + i2;
                    if (r < M) hp[(size_t)r * DIM + col] = f2bf(aa[i2]);
                }
            }
        } else if (!HAS_SKIP) {                    // layer 0, slot 3: store bf16 out
            f32x4 a0 = {0.f, 0.f, 0.f, 0.f}, a1 = {0.f, 0.f, 0.f, 0.f};
            #pragma unroll
            for (int ks = 0; ks < 4; ++ks) {
                a0 = __builtin_amdgcn_mfma_f32_16x16x32_bf16(af[0][ks], bc[ks], a0, 0, 0, 0);
                a1 = __builtin_amdgcn_mfma_f32_16x16x32_bf16(af[1][ks], bc[ks], a1, 0, 0, 0);
            }
            float bb = bconv[col] + bskip[col];
            unsigned short* op = (unsigned short*)outp;
            #pragma unroll
            for (int rg = 0; rg < 2; ++rg) {
                f32x4& aa = rg ? a1 : a0;
                #pragma unroll
                for (int i2 = 0; i2 < 4; ++i2) {
                    int r = r0 + rg * 16 + lhi * 4 + i2;
                    if (r < M) op[(size_t)r * DIM + col] = f2bf(aa[i2] + bb);
                }
            }
        } else if (slot == 3) {                    // layer 1: hold root result
            f32x4 z = {0.f, 0.f, 0.f, 0.f};
            acc34[0][n] = z; acc34[1][n] = z;
            #pragma unroll
            for (int ks = 0; ks < 4; ++ks) {
                acc34[0][n] = __builtin_amdgcn_mfma_f32_16x16x32_bf16(af[0][ks], bc[ks], acc34[0][n], 0, 0, 0);
                acc34[1][n] = __builtin_amdgcn_mfma_f32_16x16x32_bf16(af[1][ks], bc[ks], acc34[1][n], 0, 0, 0);
            }
        } else {                                   // layer 1, slot 4: += skip, store f32
            #pragma unroll
            for (int ks = 0; ks < 4; ++ks) {
                acc34[0][n] = __builtin_amdgcn_mfma_f32_16x16x32_bf16(xf[0][ks], bc[ks], acc34[0][n], 0, 0, 0);
                acc34[1][n] = __builtin_amdgcn_mfma_f32_16x16x32_bf16(xf[1][ks], bc[ks], acc34[1][n], 0, 0, 0);
            }
            float bb = bconv[col] + bskip[col];
            float* op = (float*)outp;
            #pragma unroll
            for (int rg = 0; rg < 2; ++rg) {
                #pragma unroll
                for (int i2 = 0; i2 < 4; ++i2) {
                    int r = r0 + rg * 16 + lhi * 4 + i2;
                    if (r < M) op[(size_t)r * DIM + col] = acc34[rg][n][i2] + bb;
                }
            }
        }
    }
}

// ---------------- aggregation: 4 edges in flight per wave ------------------
// BF16IO: base/out buffer is bf16 (layer 0); else f32 (layer 1, d_out).
template<bool BF16IO>
__global__ __launch_bounds__(256) void agg_kernel(
    const unsigned short* __restrict__ hr, const unsigned* __restrict__ csr,
    const int* __restrict__ offsets, float* __restrict__ outf,
    unsigned short* __restrict__ outb, int N) {
    int t = threadIdx.x;
    int lane = t & 63;
    int v = blockIdx.x * 4 + (t >> 6);
    if (v >= N) return;
    int g = lane >> 4;
    int l16 = lane & 15;
    int beg = offsets[v], end = offsets[v + 1];

    float acc[8] = {0.f, 0.f, 0.f, 0.f, 0.f, 0.f, 0.f, 0.f};
    int i = beg + g;
    bool valid = i < end;
    unsigned st = valid ? csr[i] : 0u;
    while (__any(valid)) {
        int ni = i + 4;
        bool nv = ni < end;
        unsigned nst = nv ? csr[ni] : 0u;          // prefetch next descriptor
        if (valid) {
            int srcn = st & 0xFFFF;
            int rel  = (st >> 16) & 3;
            float w  = (float)(st >> 18) * (1.0f / 16383.0f);
            const unsigned short* row = hr + ((size_t)rel * N + srcn) * DIM + l16 * 8;
            uint4 pv = *reinterpret_cast<const uint4*>(row);
            acc[0] += w * bflo(pv.x); acc[1] += w * bfhi(pv.x);
            acc[2] += w * bflo(pv.y); acc[3] += w * bfhi(pv.y);
            acc[4] += w * bflo(pv.z); acc[5] += w * bfhi(pv.z);
            acc[6] += w * bflo(pv.w); acc[7] += w * bfhi(pv.w);
        }
        i = ni; st = nst; valid = nv;
    }
    #pragma unroll
    for (int j = 0; j < 8; ++j) {
        acc[j] += __shfl_xor(acc[j], 16);
        acc[j] += __shfl_xor(acc[j], 32);
    }
    if (g == 0) {
        if (BF16IO) {
            unsigned short* op = outb + (size_t)v * DIM + l16 * 8;
            uint4 cur = *reinterpret_cast<const uint4*>(op);
            float r0 = bflo(cur.x) + acc[0], r1 = bfhi(cur.x) + acc[1];
            float r2 = bflo(cur.y) + acc[2], r3 = bfhi(cur.y) + acc[3];
            float r4 = bflo(cur.z) + acc[4], r5 = bfhi(cur.z) + acc[5];
            float r6 = bflo(cur.w) + acc[6], r7 = bfhi(cur.w) + acc[7];
            uint4 o;
            o.x = (unsigned)f2bf(r0) | ((unsigned)f2bf(r1) << 16);
            o.y = (unsigned)f2bf(r2) | ((unsigned)f2bf(r3) << 16);
            o.z = (unsigned)f2bf(r4) | ((unsigned)f2bf(r5) << 16);
            o.w = (unsigned)f2bf(r6) | ((unsigned)f2bf(r7) << 16);
            *reinterpret_cast<uint4*>(op) = o;
        } else {
            float* op = outf + (size_t)v * DIM + l16 * 8;
            float4 c0 = *reinterpret_cast<float4*>(op);
            float4 c1 = *reinterpret_cast<float4*>(op + 4);
            c0.x += acc[0]; c0.y += acc[1]; c0.z += acc[2]; c0.w += acc[3];
            c1.x += acc[4]; c1.y += acc[5]; c1.z += acc[6]; c1.w += acc[7];
            *reinterpret_cast<float4*>(op) = c0;
            *reinterpret_cast<float4*>(op + 4) = c1;
        }
    }
}

// ---------------------------------------------------------------------------
extern "C" void kernel_launch(void* const* d_in, const int* in_sizes, int n_in,
                              void* d_out, int out_size, void* d_ws, size_t ws_size,
                              hipStream_t stream) {
    const float* x       = (const float*)d_in[0];
    const int*   eidx    = (const int*)d_in[1];
    const int*   etype   = (const int*)d_in[2];
    const float* ew      = (const float*)d_in[3];
    const float* w_rel   = (const float*)d_in[4];
    const float* w_root  = (const float*)d_in[5];
    const float* b_conv  = (const float*)d_in[6];
    const float* w_skip  = (const float*)d_in[7];
    const float* b_skip  = (const float*)d_in[8];

    const int N = in_sizes[0] / DIM;          // 50000
    const int E = in_sizes[3];                // 600000
    const int* src = eidx;
    const int* dst = eidx + E;
    const int nblk = (N + 255) / 256;         // 196

    // ---- workspace carve (~67.3 MB) ----
    char* w = (char*)d_ws;
    unsigned short* WTf  = (unsigned short*)w;  w += (size_t)2 * 5 * DIM * DIM * 2;
    unsigned short* xb   = (unsigned short*)w;  w += (size_t)N * DIM * 2;            // 12.8MB
    unsigned short* hr   = (unsigned short*)w;  w += (size_t)3 * N * DIM * 2;        // 38.4MB
    unsigned short* h1   = (unsigned short*)w;  w += (size_t)N * DIM * 2;            // 12.8MB
    int* counts          = (int*)w;             w += (size_t)N * 4;
    int* offsets         = (int*)w;             w += (size_t)(N + 4) * 4;
    int* cursor          = (int*)w;             w += (size_t)N * 4;
    int* bsums           = (int*)w;             w += (size_t)256 * 4;
    int* bpre            = (int*)w;             w += (size_t)256 * 4;
    unsigned* csr        = (unsigned*)w;        w += (size_t)E * 4;

    float* out = (float*)d_out;

    hipMemsetAsync(counts, 0, (size_t)N * sizeof(int), stream);
    conv_bf16<<<(N * DIM / 8 + 255) / 256, 256, 0, stream>>>(x, xb, N * DIM / 8);
    prep_w<<<(2 * 5 * DIM * DIM + 255) / 256, 256, 0, stream>>>(w_rel, w_root, w_skip, WTf);
    count_kernel<<<(E + 255) / 256, 256, 0, stream>>>(dst, counts, E);
    bsum_kernel<<<nblk, 256, 0, stream>>>(counts, bsums, N);
    bscan_kernel<<<1, 256, 0, stream>>>(bsums, bpre, nblk);
    scan_final<<<nblk, 256, 0, stream>>>(counts, bpre, offsets, cursor, N, E);
    scatter_kernel<<<(E + 255) / 256, 256, 0, stream>>>(src, dst, etype, ew,
                                                        cursor, (unsigned*)csr, E);
    int gblocks = (N + 127) / 128;
    int ablocks = (N + 3) / 4;
    // ---- layer 0 (root+skip merged; bf16 out) ----
    multi_gemm<false, true><<<gblocks, 256, 0, stream>>>(xb, nullptr, WTf,
                                                         b_conv, b_skip, hr, h1, N);
    agg_kernel<true><<<ablocks, 256, 0, stream>>>(hr, csr, offsets, nullptr, h1, N);
    // ---- layer 1 (root from h1, skip from xb; f32 out) ----
    multi_gemm<true, false><<<gblocks, 256, 0, stream>>>(h1, xb, WTf + (size_t)5 * DIM * DIM,
                                                         b_conv + DIM, b_skip + DIM, hr, out, N);
    agg_kernel<false><<<ablocks, 256, 0, stream>>>(hr, csr, offsets, out, nullptr, N);
}